// Round 4
// baseline (601.509 us; speedup 1.0000x reference)
//
#include <hip/hip_runtime.h>
#include <hip/hip_bf16.h>

typedef unsigned short u16;
typedef unsigned int   u32;

// bf16 (stored as u16) <-> f32. Decode exact; encode round-to-nearest-even.
__device__ __forceinline__ float b2f(u16 v){ return __uint_as_float(((u32)v) << 16); }
__device__ __forceinline__ u16   f2b(float f){
  u32 u = __float_as_uint(f);
  u += 0x7fffu + ((u >> 16) & 1u);
  return (u16)(u >> 16);
}
__device__ __forceinline__ float gelu_exact(float x){
  return 0.5f * x * (1.0f + erff(x * 0.70710678118654752440f));
}

// Workspace float offsets for prepped weight tables (16B-aligned blocks)
#define WTG_OFF   0          // fc1 w1^T: [k][p][28], k<15,p<54 -> 22680 f
#define W2G_OFF   22720      // fc1 w2 padded: [l][s][28], 27 rows -> 11340 f
#define W12G_OFF  34112      // fc2 w1 padded: [k][j][28], 9 rows -> 3780 f
#define PREP_F    37952      // total floats (151808 B, 16B-aligned)

// ---------------------------------------------------------------------------
// K0 (prep): build padded/transposed weight tables in workspace. Runs once.
//  wtg [k][p][j]: p<54(z-pad), j<28(z-pad)   from w1[(k*27+j)*53+p]
//  w2g [l][s][r]: r padded to 28             from w2[(l*27+s)*27+r]
//  w12g[k][j][p]: p padded to 28             from w1_2[(k*9+j)*27+p]
// ---------------------------------------------------------------------------
__global__ __launch_bounds__(256) void k_prep(
    const float* __restrict__ w1, const float* __restrict__ w2,
    const float* __restrict__ w1_2, float* __restrict__ ws)
{
  int tid = blockIdx.x*256 + threadIdx.x;
  for (int e = tid; e < 15*54*28; e += gridDim.x*256){
    int kk = e / 1512, rem = e - kk*1512;
    int p = rem / 28, j = rem - p*28;
    ws[WTG_OFF + e] = (p < 53 && j < 27) ? w1[(kk*27 + j)*53 + p] : 0.0f;
  }
  for (int e = tid; e < 15*27*28; e += gridDim.x*256){
    int l = e / 756, rem = e - l*756;
    int s = rem / 28, r = rem - s*28;
    ws[W2G_OFF + e] = (r < 27) ? w2[(l*27 + s)*27 + r] : 0.0f;
  }
  for (int e = tid; e < 15*9*28; e += gridDim.x*256){
    int kk = e / 252, rem = e - kk*252;
    int j = rem / 28, p = rem - j*28;
    ws[W12G_OFF + e] = (p < 27) ? w1_2[(kk*9 + j)*27 + p] : 0.0f;
  }
}

// ---------------------------------------------------------------------------
// K1 (fc1a) v4: 2 rows/thread (128-thr block, 256-row tile).
// v3 post-mortem: 4 FMA per 16B weight-load-inst; 60 waves/CU x 378 loads
// ~47us/CU on the memory-issue pipe (dur 147, VALU 43%). v4: each weight
// float4 feeds 8 FMAs (2 rows); per-CU load-issue halves; FMA total invariant.
// Per-row FMA order identical to v3 -> bit-identical output.
// ---------------------------------------------------------------------------
__global__ __launch_bounds__(128, 3) void k_fc1a(
    const float* __restrict__ x, const float* __restrict__ wtg,
    u16* __restrict__ act, int base, int Bc)
{
  __shared__ u32 xsu[256*27];     // row stride 27 u32 (odd -> conflict-free)
  const int tid = threadIdx.x;
  const int k   = blockIdx.y;
  const int rowloc = blockIdx.x * 256;

  // stage x tile: 256 rows x 53 cols as 27 packed-bf16 dwords per row
  #pragma unroll 4
  for (int i = 0; i < 54; ++i){
    int e = i*128 + tid;                 // < 6912
    int r = e / 27, c2 = e - r*27;
    int col = k*53 + 2*c2;               // 2*c2 <= 52 < 53 always
    const size_t rowoff = (size_t)(base + rowloc + r)*784;
    float v0 = 0.f, v1 = 0.f;
    if (col < 784) v0 = x[rowoff + col];
    if (2*c2+1 < 53 && col+1 < 784) v1 = x[rowoff + col + 1];
    xsu[e] = (u32)f2b(v0) | ((u32)f2b(v1) << 16);
  }
  __syncthreads();

  float acc0[28], acc1[28];
  #pragma unroll
  for (int j = 0; j < 28; ++j){ acc0[j] = 0.0f; acc1[j] = 0.0f; }

  const float* __restrict__ wk = wtg + (size_t)k*1512;   // 54*28
  const u32* xrow0 = &xsu[tid*27];
  const u32* xrow1 = &xsu[(tid+128)*27];
  #pragma unroll
  for (int pp = 0; pp < 27; ++pp){
    const u32 xa = xrow0[pp];
    const u32 xb = xrow1[pp];
    const float x00 = __uint_as_float(xa << 16);          // row0, p=2pp
    const float x01 = __uint_as_float(xa & 0xffff0000u);  // row0, p=2pp+1
    const float x10 = __uint_as_float(xb << 16);          // row1, p=2pp
    const float x11 = __uint_as_float(xb & 0xffff0000u);  // row1, p=2pp+1
    const float4* wa = (const float4*)(wk + 56*pp);       // row 2pp   (28 f)
    const float4* wb = (const float4*)(wk + 56*pp + 28);  // row 2pp+1 (28 f)
    #pragma unroll
    for (int i = 0; i < 7; ++i){
      const float4 a = wa[i];
      const float4 b = wb[i];
      acc0[4*i+0] = fmaf(a.x, x00, fmaf(b.x, x01, acc0[4*i+0]));
      acc0[4*i+1] = fmaf(a.y, x00, fmaf(b.y, x01, acc0[4*i+1]));
      acc0[4*i+2] = fmaf(a.z, x00, fmaf(b.z, x01, acc0[4*i+2]));
      acc0[4*i+3] = fmaf(a.w, x00, fmaf(b.w, x01, acc0[4*i+3]));
      acc1[4*i+0] = fmaf(a.x, x10, fmaf(b.x, x11, acc1[4*i+0]));
      acc1[4*i+1] = fmaf(a.y, x10, fmaf(b.y, x11, acc1[4*i+1]));
      acc1[4*i+2] = fmaf(a.z, x10, fmaf(b.z, x11, acc1[4*i+2]));
      acc1[4*i+3] = fmaf(a.w, x10, fmaf(b.w, x11, acc1[4*i+3]));
    }
  }
  const int r0 = rowloc + tid;
  #pragma unroll
  for (int j = 0; j < 27; ++j){
    const size_t bf = (size_t)(k*27 + j)*Bc;
    act[bf + r0]       = f2b(acc0[j]);
    act[bf + r0 + 128] = f2b(acc1[j]);
  }
}

// ---------------------------------------------------------------------------
// K2 (fc1b) v2: weights via uniform GLOBAL reads (w2g, padded 28), 2 rows/
// thread, no LDS. v1 had 189 broadcast ds_read_b128/thread (~57us/CU LDS pipe).
// In-place on act: block covers rows [bx*256,+256); all reads precede writes.
// ---------------------------------------------------------------------------
__global__ __launch_bounds__(128, 3) void k_fc1b(
    const float* __restrict__ w2g, const float* __restrict__ b1,
    u16* act, int Bc)
{
  const int tid = threadIdx.x;
  const int l   = blockIdx.y;
  const int row0 = blockIdx.x*256 + tid;
  const float* __restrict__ wl = w2g + (size_t)l*756;   // 27*28

  float t0[28], t1[28];
  #pragma unroll
  for (int r = 0; r < 27; ++r){
    t0[r] = b2f(act[(size_t)(r*15 + l)*Bc + row0]);
    t1[r] = b2f(act[(size_t)(r*15 + l)*Bc + row0 + 128]);
  }
  t0[27] = 0.0f; t1[27] = 0.0f;
  #pragma unroll
  for (int s = 0; s < 27; ++s){
    const float4* wp = (const float4*)(wl + s*28);
    float va0=0.f, vb0=0.f, va1=0.f, vb1=0.f;
    #pragma unroll
    for (int i = 0; i < 7; ++i){
      const float4 w = wp[i];
      va0 = fmaf(w.x, t0[4*i+0], va0); vb0 = fmaf(w.y, t0[4*i+1], vb0);
      va0 = fmaf(w.z, t0[4*i+2], va0); vb0 = fmaf(w.w, t0[4*i+3], vb0);
      va1 = fmaf(w.x, t1[4*i+0], va1); vb1 = fmaf(w.y, t1[4*i+1], vb1);
      va1 = fmaf(w.z, t1[4*i+2], va1); vb1 = fmaf(w.w, t1[4*i+3], vb1);
    }
    const int m = s*15 + l;
    const float bb = (m < 392) ? b1[m] : 0.0f;
    const float h0 = (m < 392) ? gelu_exact(va0 + vb0 + bb) : 0.0f;
    const float h1 = (m < 392) ? gelu_exact(va1 + vb1 + bb) : 0.0f;
    act[(size_t)m*Bc + row0]       = f2b(h0);
    act[(size_t)m*Bc + row0 + 128] = f2b(h1);
  }
}

// ---------------------------------------------------------------------------
// K3 (fc2a) v2: weights via uniform GLOBAL reads (w12g), 2 rows/thread.
// ---------------------------------------------------------------------------
__global__ __launch_bounds__(128, 3) void k_fc2a(
    const u16* __restrict__ h1t, const float* __restrict__ w12g,
    u16* __restrict__ o2t, int Bc)
{
  const int tid = threadIdx.x;
  const int k   = blockIdx.y;
  const int row0 = blockIdx.x*256 + tid;
  const float* __restrict__ wk = w12g + (size_t)k*252;  // 9*28

  float h0[28], h1[28];
  #pragma unroll
  for (int p = 0; p < 27; ++p){
    h0[p] = b2f(h1t[(size_t)(k*27 + p)*Bc + row0]);
    h1[p] = b2f(h1t[(size_t)(k*27 + p)*Bc + row0 + 128]);
  }
  h0[27] = 0.0f; h1[27] = 0.0f;
  #pragma unroll
  for (int j = 0; j < 9; ++j){
    const float4* wp = (const float4*)(wk + j*28);
    float va0=0.f, vb0=0.f, va1=0.f, vb1=0.f;
    #pragma unroll
    for (int i = 0; i < 7; ++i){
      const float4 w = wp[i];
      va0 = fmaf(w.x, h0[4*i+0], va0); vb0 = fmaf(w.y, h0[4*i+1], vb0);
      va0 = fmaf(w.z, h0[4*i+2], va0); vb0 = fmaf(w.w, h0[4*i+3], vb0);
      va1 = fmaf(w.x, h1[4*i+0], va1); vb1 = fmaf(w.y, h1[4*i+1], vb1);
      va1 = fmaf(w.z, h1[4*i+2], va1); vb1 = fmaf(w.w, h1[4*i+3], vb1);
    }
    const size_t bf = (size_t)(k*9 + j)*Bc;
    o2t[bf + row0]       = f2b(va0 + vb0);
    o2t[bf + row0 + 128] = f2b(va1 + vb1);
  }
}

// ---------------------------------------------------------------------------
// K4 (fc2b) v2: weights/bias via uniform global reads (layout already fits).
// ---------------------------------------------------------------------------
__global__ __launch_bounds__(256) void k_fc2b(
    const u16* __restrict__ o2t, const float* __restrict__ w2_2,
    const float* __restrict__ b2, u16* __restrict__ h2t, int Bc)
{
  const int tid = threadIdx.x;
  const int l   = blockIdx.y;
  const float* __restrict__ wl = w2_2 + (size_t)l*81;

  const int row = blockIdx.x*256 + tid;
  float t[9];
  #pragma unroll
  for (int r = 0; r < 9; ++r) t[r] = b2f(o2t[(size_t)(r*15 + l)*Bc + row]);
  #pragma unroll
  for (int s = 0; s < 9; ++s){
    float v = 0.f;
    #pragma unroll
    for (int r = 0; r < 9; ++r) v = fmaf(wl[s*9 + r], t[r], v);
    const int m = s*15 + l;
    float h = (m < 128) ? gelu_exact(v + b2[m < 128 ? m : 0]) : 0.0f;
    h2t[(size_t)m*Bc + row] = f2b(h);
  }
}

// ---------------------------------------------------------------------------
// K5 (fc3a) v2: weights via uniform global reads.
// ---------------------------------------------------------------------------
__global__ __launch_bounds__(256) void k_fc3a(
    const u16* __restrict__ h2t, const float* __restrict__ w1_3,
    u16* __restrict__ o3t, int Bc)
{
  const int tid = threadIdx.x;
  const int k   = blockIdx.y;
  const float* __restrict__ wk = w1_3 + (size_t)k*45;

  const int row = blockIdx.x*256 + tid;
  float hb[9];
  #pragma unroll
  for (int p = 0; p < 9; ++p) hb[p] = b2f(h2t[(size_t)(k*9 + p)*Bc + row]);
  #pragma unroll
  for (int j = 0; j < 5; ++j){
    float v = 0.f;
    #pragma unroll
    for (int p = 0; p < 9; ++p) v = fmaf(wk[j*9 + p], hb[p], v);
    o3t[(size_t)(k*5 + j)*Bc + row] = f2b(v);
  }
}

// ---------------------------------------------------------------------------
// K6 (fc3b + fc4 + log_softmax) v2: weights/biases via uniform global reads
// (all indices uniform in l,s,c); only outS kept in LDS for coalesced stores.
// ---------------------------------------------------------------------------
__global__ __launch_bounds__(256) void k_fc3b4(
    const u16* __restrict__ o3t,
    const float* __restrict__ w2_3, const float* __restrict__ b3,
    const float* __restrict__ w1_4, const float* __restrict__ w2_4, const float* __restrict__ b4,
    float* __restrict__ out, int base, int Bc)
{
  __shared__ float outS[256*10];
  const int tid = threadIdx.x;
  const int rloc = blockIdx.x*256 + tid;

  float sacc[10];
  #pragma unroll
  for (int c = 0; c < 10; ++c) sacc[c] = 0.0f;

  #pragma unroll
  for (int l = 0; l < 15; ++l){
    float t[5];
    #pragma unroll
    for (int r = 0; r < 5; ++r) t[r] = b2f(o3t[(size_t)(r*15 + l)*Bc + rloc]);
    #pragma unroll
    for (int s = 0; s < 5; ++s){
      const int m = s*15 + l;
      if (m < 50){
        const float* wp = w2_3 + (l*5 + s)*5;
        float v = 0.f;
        v = fmaf(wp[0], t[0], v); v = fmaf(wp[1], t[1], v);
        v = fmaf(wp[2], t[2], v); v = fmaf(wp[3], t[3], v);
        v = fmaf(wp[4], t[4], v);
        const float h = gelu_exact(v + b3[m]);
        const int c = m / 5, p = m - (m/5)*5;      // compile-time constants
        sacc[c] = fmaf(h, w1_4[c*5 + p], sacc[c]);
      }
    }
  }
  float v[10];
  #pragma unroll
  for (int c = 0; c < 10; ++c) v[c] = fmaf(sacc[c], w2_4[c], b4[c]);

  float mx = v[0];
  #pragma unroll
  for (int c = 1; c < 10; ++c) mx = fmaxf(mx, v[c]);
  float sum = 0.f;
  #pragma unroll
  for (int c = 0; c < 10; ++c) sum += expf(v[c] - mx);
  const float lse = mx + logf(sum);
  #pragma unroll
  for (int c = 0; c < 10; ++c) outS[tid*10 + c] = v[c] - lse;
  __syncthreads();
  const size_t blockOut = (size_t)(base + blockIdx.x*256) * 10;
  #pragma unroll
  for (int i = 0; i < 10; ++i){
    int e = i*256 + tid;
    out[blockOut + e] = outS[e];
  }
}

// ---------------------------------------------------------------------------
extern "C" void kernel_launch(void* const* d_in, const int* in_sizes, int n_in,
                              void* d_out, int out_size, void* d_ws, size_t ws_size,
                              hipStream_t stream)
{
  const float* x     = (const float*)d_in[0];
  const float* f1w1  = (const float*)d_in[1];
  const float* f1w2  = (const float*)d_in[2];
  const float* f1b   = (const float*)d_in[3];
  const float* f2w1  = (const float*)d_in[4];
  const float* f2w2  = (const float*)d_in[5];
  const float* f2b   = (const float*)d_in[6];
  const float* f3w1  = (const float*)d_in[7];
  const float* f3w2  = (const float*)d_in[8];
  const float* f3b   = (const float*)d_in[9];
  const float* f4w1  = (const float*)d_in[10];
  const float* f4w2  = (const float*)d_in[11];
  const float* f4b   = (const float*)d_in[12];
  const int B = in_sizes[0] / 784;           // 65536
  (void)n_in; (void)out_size;

  // ws layout: [prep tables: PREP_F floats = 151808 B]
  //            [act 405 | o2t 135 | h2t 135 | o3t 75 u16 per row = 1500 B/row]
  const size_t prepBytes = (size_t)PREP_F * sizeof(float);
  float* wsF  = (float*)d_ws;
  u16*  wsAct = (u16*)((char*)d_ws + prepBytes);

  k_prep<<<dim3(32), 256, 0, stream>>>(f1w1, f1w2, f2w1, wsF);

  const float* wtg  = wsF + WTG_OFF;
  const float* w2g  = wsF + W2G_OFF;
  const float* w12g = wsF + W12G_OFF;

  const size_t perRow = 750 * sizeof(u16);
  int Rc = B;
  if (ws_size - prepBytes < (size_t)B * perRow){
    size_t rows = (ws_size - prepBytes) / perRow;
    Rc = (int)(rows & ~(size_t)511);
    if (Rc < 512) Rc = 512;
  }
  for (int base = 0; base < B; base += Rc){
    const int Bc = (B - base < Rc) ? (B - base) : Rc;
    u16* act = wsAct;
    u16* o2t = act + (size_t)405 * Bc;
    u16* h2t = o2t + (size_t)135 * Bc;
    u16* o3t = h2t + (size_t)135 * Bc;
    k_fc1a<<<dim3(Bc/256, 15), 128, 0, stream>>>(x, wtg, act, base, Bc);
    k_fc1b<<<dim3(Bc/256, 15), 128, 0, stream>>>(w2g, f1b, act, Bc);
    k_fc2a<<<dim3(Bc/256, 15), 128, 0, stream>>>(act, w12g, o2t, Bc);
    k_fc2b<<<dim3(Bc/256, 15), 256, 0, stream>>>(o2t, f2w2, f2b, h2t, Bc);
    k_fc3a<<<dim3(Bc/256, 15), 256, 0, stream>>>(h2t, f3w1, o3t, Bc);
    k_fc3b4<<<dim3(Bc/256), 256, 0, stream>>>(o3t, f3w2, f3b,
                                              f4w1, f4w2, f4b, (float*)d_out, base, Bc);
  }
}

// Round 5
// 462.068 us; speedup vs baseline: 1.3018x; 1.3018x over previous
//
#include <hip/hip_runtime.h>
#include <hip/hip_bf16.h>

typedef unsigned short u16;
typedef unsigned int   u32;

// bf16 (stored as u16) <-> f32. Decode exact; encode round-to-nearest-even.
__device__ __forceinline__ float b2f(u16 v){ return __uint_as_float(((u32)v) << 16); }
__device__ __forceinline__ u16   f2b(float f){
  u32 u = __float_as_uint(f);
  u += 0x7fffu + ((u >> 16) & 1u);
  return (u16)(u >> 16);
}
__device__ __forceinline__ float gelu_exact(float x){
  return 0.5f * x * (1.0f + erff(x * 0.70710678118654752440f));
}

// Workspace float offsets for prepped weight tables (16B-aligned blocks)
#define WTG_OFF   0          // fc1 w1^T: [k][p][28], k<15,p<54 -> 22680 f
#define W2G_OFF   22720      // fc1 w2 padded: [l][s][28], 27 rows -> 11340 f
#define W12G_OFF  34112      // fc2 w1 padded: [k][j][28], 9 rows -> 3780 f
#define PREP_F    37952      // total floats (151808 B, 16B-aligned)

// ---------------------------------------------------------------------------
// K0 (prep): build padded/transposed weight tables in workspace. Runs once.
// ---------------------------------------------------------------------------
__global__ __launch_bounds__(256) void k_prep(
    const float* __restrict__ w1, const float* __restrict__ w2,
    const float* __restrict__ w1_2, float* __restrict__ ws)
{
  int tid = blockIdx.x*256 + threadIdx.x;
  for (int e = tid; e < 15*54*28; e += gridDim.x*256){
    int kk = e / 1512, rem = e - kk*1512;
    int p = rem / 28, j = rem - p*28;
    ws[WTG_OFF + e] = (p < 53 && j < 27) ? w1[(kk*27 + j)*53 + p] : 0.0f;
  }
  for (int e = tid; e < 15*27*28; e += gridDim.x*256){
    int l = e / 756, rem = e - l*756;
    int s = rem / 28, r = rem - s*28;
    ws[W2G_OFF + e] = (r < 27) ? w2[(l*27 + s)*27 + r] : 0.0f;
  }
  for (int e = tid; e < 15*9*28; e += gridDim.x*256){
    int kk = e / 252, rem = e - kk*252;
    int j = rem / 28, p = rem - j*28;
    ws[W12G_OFF + e] = (p < 27) ? w1_2[(kk*9 + j)*27 + p] : 0.0f;
  }
}

// ---------------------------------------------------------------------------
// K1 (fc1a) v5 == v3 revert (known 147us, occ 54%, VALU 43%).
// v4 post-mortem: 128-thr/2-row kept LDS 27.6KB -> only 5 blocks(10 waves)/CU
// vs v3's 20 waves; VALU-busy TIME identical (63us) -> dur = busy/VALUBusy.
// Occupancy is the binding resource; revert to 256 thr, 1 row/thread.
// out1[row][f], f=k*27+j = sum_{p<53} xe[row][k*53+p]*w1[k][j][p]
// act column-major bf16: act[f*Bc + row]. Grid (Bc/256, 15), block 256.
// ---------------------------------------------------------------------------
__global__ __launch_bounds__(256, 5) void k_fc1a(
    const float* __restrict__ x, const float* __restrict__ wtg,
    u16* __restrict__ act, int base, int Bc)
{
  __shared__ u32 xsu[256*27];     // row stride 27 u32 (odd -> conflict-free)
  const int tid = threadIdx.x;
  const int k   = blockIdx.y;
  const int rowloc = blockIdx.x * 256;

  // stage x tile: 256 rows x 53 cols as 27 packed-bf16 dwords per row
  #pragma unroll 4
  for (int i = 0; i < 27; ++i){
    int e = i*256 + tid;                 // < 6912
    int r = e / 27, c2 = e - r*27;
    int col = k*53 + 2*c2;               // 2*c2 <= 52 < 53 always
    const size_t rowoff = (size_t)(base + rowloc + r)*784;
    float v0 = 0.f, v1 = 0.f;
    if (col < 784) v0 = x[rowoff + col];
    if (2*c2+1 < 53 && col+1 < 784) v1 = x[rowoff + col + 1];
    xsu[e] = (u32)f2b(v0) | ((u32)f2b(v1) << 16);
  }
  __syncthreads();

  float acc[28];
  #pragma unroll
  for (int j = 0; j < 28; ++j) acc[j] = 0.0f;

  const float* __restrict__ wk = wtg + (size_t)k*1512;   // 54*28
  const u32* xrow = &xsu[tid*27];
  #pragma unroll
  for (int pp = 0; pp < 27; ++pp){
    const u32 xv2 = xrow[pp];
    const float x0 = __uint_as_float(xv2 << 16);          // p = 2pp
    const float x1 = __uint_as_float(xv2 & 0xffff0000u);  // p = 2pp+1
    const float4* wa = (const float4*)(wk + 56*pp);       // row 2pp   (28 f)
    const float4* wb = (const float4*)(wk + 56*pp + 28);  // row 2pp+1 (28 f)
    #pragma unroll
    for (int i = 0; i < 7; ++i){
      const float4 a = wa[i];
      const float4 b = wb[i];
      acc[4*i+0] = fmaf(a.x, x0, fmaf(b.x, x1, acc[4*i+0]));
      acc[4*i+1] = fmaf(a.y, x0, fmaf(b.y, x1, acc[4*i+1]));
      acc[4*i+2] = fmaf(a.z, x0, fmaf(b.z, x1, acc[4*i+2]));
      acc[4*i+3] = fmaf(a.w, x0, fmaf(b.w, x1, acc[4*i+3]));
    }
  }
  const int r0 = rowloc + tid;
  #pragma unroll
  for (int j = 0; j < 27; ++j)
    act[(size_t)(k*27 + j)*Bc + r0] = f2b(acc[j]);
}

// ---------------------------------------------------------------------------
// K2 (fc1b) v3: 256 thr, 1 row/thread, weights via wave-uniform GLOBAL reads
// (s_load; off both LDS and VMEM-vector pipes). No LDS -> VGPR-limited
// occupancy (high). v1 paid ~57us/CU on LDS broadcast; v2 paid occupancy.
// In-place on act: block covers its own rows only -> no cross-block hazard.
// ---------------------------------------------------------------------------
__global__ __launch_bounds__(256) void k_fc1b(
    const float* __restrict__ w2g, const float* __restrict__ b1,
    u16* act, int Bc)
{
  const int tid = threadIdx.x;
  const int l   = blockIdx.y;
  const int row = blockIdx.x*256 + tid;
  const float* __restrict__ wl = w2g + (size_t)l*756;   // 27*28

  float t[28];
  #pragma unroll
  for (int r = 0; r < 27; ++r) t[r] = b2f(act[(size_t)(r*15 + l)*Bc + row]);
  t[27] = 0.0f;
  #pragma unroll
  for (int s = 0; s < 27; ++s){
    const float4* wp = (const float4*)(wl + s*28);
    float va = 0.f, vb = 0.f;
    #pragma unroll
    for (int i = 0; i < 7; ++i){
      const float4 w = wp[i];
      va = fmaf(w.x, t[4*i+0], va); vb = fmaf(w.y, t[4*i+1], vb);
      va = fmaf(w.z, t[4*i+2], va); vb = fmaf(w.w, t[4*i+3], vb);
    }
    const int m = s*15 + l;
    const float bb = (m < 392) ? b1[m] : 0.0f;
    const float h = (m < 392) ? gelu_exact(va + vb + bb) : 0.0f;
    act[(size_t)m*Bc + row] = f2b(h);
  }
}

// ---------------------------------------------------------------------------
// K3 (fc2a) v3: 256 thr, 1 row/thread, weights via uniform global reads.
// ---------------------------------------------------------------------------
__global__ __launch_bounds__(256) void k_fc2a(
    const u16* __restrict__ h1t, const float* __restrict__ w12g,
    u16* __restrict__ o2t, int Bc)
{
  const int tid = threadIdx.x;
  const int k   = blockIdx.y;
  const int row = blockIdx.x*256 + tid;
  const float* __restrict__ wk = w12g + (size_t)k*252;  // 9*28

  float hb[28];
  #pragma unroll
  for (int p = 0; p < 27; ++p) hb[p] = b2f(h1t[(size_t)(k*27 + p)*Bc + row]);
  hb[27] = 0.0f;
  #pragma unroll
  for (int j = 0; j < 9; ++j){
    const float4* wp = (const float4*)(wk + j*28);
    float va = 0.f, vb = 0.f;
    #pragma unroll
    for (int i = 0; i < 7; ++i){
      const float4 w = wp[i];
      va = fmaf(w.x, hb[4*i+0], va); vb = fmaf(w.y, hb[4*i+1], vb);
      va = fmaf(w.z, hb[4*i+2], va); vb = fmaf(w.w, hb[4*i+3], vb);
    }
    o2t[(size_t)(k*9 + j)*Bc + row] = f2b(va + vb);
  }
}

// ---------------------------------------------------------------------------
// K4 (fc2b) v2: weights/bias via uniform global reads.
// ---------------------------------------------------------------------------
__global__ __launch_bounds__(256) void k_fc2b(
    const u16* __restrict__ o2t, const float* __restrict__ w2_2,
    const float* __restrict__ b2, u16* __restrict__ h2t, int Bc)
{
  const int tid = threadIdx.x;
  const int l   = blockIdx.y;
  const float* __restrict__ wl = w2_2 + (size_t)l*81;

  const int row = blockIdx.x*256 + tid;
  float t[9];
  #pragma unroll
  for (int r = 0; r < 9; ++r) t[r] = b2f(o2t[(size_t)(r*15 + l)*Bc + row]);
  #pragma unroll
  for (int s = 0; s < 9; ++s){
    float v = 0.f;
    #pragma unroll
    for (int r = 0; r < 9; ++r) v = fmaf(wl[s*9 + r], t[r], v);
    const int m = s*15 + l;
    float h = (m < 128) ? gelu_exact(v + b2[m < 128 ? m : 0]) : 0.0f;
    h2t[(size_t)m*Bc + row] = f2b(h);
  }
}

// ---------------------------------------------------------------------------
// K5 (fc3a) v2: weights via uniform global reads.
// ---------------------------------------------------------------------------
__global__ __launch_bounds__(256) void k_fc3a(
    const u16* __restrict__ h2t, const float* __restrict__ w1_3,
    u16* __restrict__ o3t, int Bc)
{
  const int tid = threadIdx.x;
  const int k   = blockIdx.y;
  const float* __restrict__ wk = w1_3 + (size_t)k*45;

  const int row = blockIdx.x*256 + tid;
  float hb[9];
  #pragma unroll
  for (int p = 0; p < 9; ++p) hb[p] = b2f(h2t[(size_t)(k*9 + p)*Bc + row]);
  #pragma unroll
  for (int j = 0; j < 5; ++j){
    float v = 0.f;
    #pragma unroll
    for (int p = 0; p < 9; ++p) v = fmaf(wk[j*9 + p], hb[p], v);
    o3t[(size_t)(k*5 + j)*Bc + row] = f2b(v);
  }
}

// ---------------------------------------------------------------------------
// K6 (fc3b + fc4 + log_softmax) v2: weights/biases via uniform global reads;
// only outS in LDS for coalesced f32 stores.
// ---------------------------------------------------------------------------
__global__ __launch_bounds__(256) void k_fc3b4(
    const u16* __restrict__ o3t,
    const float* __restrict__ w2_3, const float* __restrict__ b3,
    const float* __restrict__ w1_4, const float* __restrict__ w2_4, const float* __restrict__ b4,
    float* __restrict__ out, int base, int Bc)
{
  __shared__ float outS[256*10];
  const int tid = threadIdx.x;
  const int rloc = blockIdx.x*256 + tid;

  float sacc[10];
  #pragma unroll
  for (int c = 0; c < 10; ++c) sacc[c] = 0.0f;

  #pragma unroll
  for (int l = 0; l < 15; ++l){
    float t[5];
    #pragma unroll
    for (int r = 0; r < 5; ++r) t[r] = b2f(o3t[(size_t)(r*15 + l)*Bc + rloc]);
    #pragma unroll
    for (int s = 0; s < 5; ++s){
      const int m = s*15 + l;
      if (m < 50){
        const float* wp = w2_3 + (l*5 + s)*5;
        float v = 0.f;
        v = fmaf(wp[0], t[0], v); v = fmaf(wp[1], t[1], v);
        v = fmaf(wp[2], t[2], v); v = fmaf(wp[3], t[3], v);
        v = fmaf(wp[4], t[4], v);
        const float h = gelu_exact(v + b3[m]);
        const int c = m / 5, p = m - (m/5)*5;      // compile-time constants
        sacc[c] = fmaf(h, w1_4[c*5 + p], sacc[c]);
      }
    }
  }
  float v[10];
  #pragma unroll
  for (int c = 0; c < 10; ++c) v[c] = fmaf(sacc[c], w2_4[c], b4[c]);

  float mx = v[0];
  #pragma unroll
  for (int c = 1; c < 10; ++c) mx = fmaxf(mx, v[c]);
  float sum = 0.f;
  #pragma unroll
  for (int c = 0; c < 10; ++c) sum += expf(v[c] - mx);
  const float lse = mx + logf(sum);
  #pragma unroll
  for (int c = 0; c < 10; ++c) outS[tid*10 + c] = v[c] - lse;
  __syncthreads();
  const size_t blockOut = (size_t)(base + blockIdx.x*256) * 10;
  #pragma unroll
  for (int i = 0; i < 10; ++i){
    int e = i*256 + tid;
    out[blockOut + e] = outS[e];
  }
}

// ---------------------------------------------------------------------------
extern "C" void kernel_launch(void* const* d_in, const int* in_sizes, int n_in,
                              void* d_out, int out_size, void* d_ws, size_t ws_size,
                              hipStream_t stream)
{
  const float* x     = (const float*)d_in[0];
  const float* f1w1  = (const float*)d_in[1];
  const float* f1w2  = (const float*)d_in[2];
  const float* f1b   = (const float*)d_in[3];
  const float* f2w1  = (const float*)d_in[4];
  const float* f2w2  = (const float*)d_in[5];
  const float* f2b   = (const float*)d_in[6];
  const float* f3w1  = (const float*)d_in[7];
  const float* f3w2  = (const float*)d_in[8];
  const float* f3b   = (const float*)d_in[9];
  const float* f4w1  = (const float*)d_in[10];
  const float* f4w2  = (const float*)d_in[11];
  const float* f4b   = (const float*)d_in[12];
  const int B = in_sizes[0] / 784;           // 65536
  (void)n_in; (void)out_size;

  // ws layout: [prep tables: PREP_F floats = 151808 B]
  //            [act 405 | o2t 135 | h2t 135 | o3t 75 u16 per row = 1500 B/row]
  const size_t prepBytes = (size_t)PREP_F * sizeof(float);
  float* wsF  = (float*)d_ws;
  u16*  wsAct = (u16*)((char*)d_ws + prepBytes);

  k_prep<<<dim3(32), 256, 0, stream>>>(f1w1, f1w2, f2w1, wsF);

  const float* wtg  = wsF + WTG_OFF;
  const float* w2g  = wsF + W2G_OFF;
  const float* w12g = wsF + W12G_OFF;

  const size_t perRow = 750 * sizeof(u16);
  int Rc = B;
  if (ws_size - prepBytes < (size_t)B * perRow){
    size_t rows = (ws_size - prepBytes) / perRow;
    Rc = (int)(rows & ~(size_t)511);
    if (Rc < 512) Rc = 512;
  }
  for (int base = 0; base < B; base += Rc){
    const int Bc = (B - base < Rc) ? (B - base) : Rc;
    u16* act = wsAct;
    u16* o2t = act + (size_t)405 * Bc;
    u16* h2t = o2t + (size_t)135 * Bc;
    u16* o3t = h2t + (size_t)135 * Bc;
    k_fc1a<<<dim3(Bc/256, 15), 256, 0, stream>>>(x, wtg, act, base, Bc);
    k_fc1b<<<dim3(Bc/256, 15), 256, 0, stream>>>(w2g, f1b, act, Bc);
    k_fc2a<<<dim3(Bc/256, 15), 256, 0, stream>>>(act, w12g, o2t, Bc);
    k_fc2b<<<dim3(Bc/256, 15), 256, 0, stream>>>(o2t, f2w2, f2b, h2t, Bc);
    k_fc3a<<<dim3(Bc/256, 15), 256, 0, stream>>>(h2t, f3w1, o3t, Bc);
    k_fc3b4<<<dim3(Bc/256), 256, 0, stream>>>(o3t, f3w2, f3b,
                                              f4w1, f4w2, f4b, (float*)d_out, base, Bc);
  }
}